// Round 1
// baseline (140.580 us; speedup 1.0000x reference)
//
#include <hip/hip_runtime.h>

// SpatialTransformer: per-batch 3x3 homography warp + bilinear sample of
// image channel 0. image: (B,128,128,3) f32, H: (B,3,3) f32,
// out: (B,128,128,1) f32. B = 2048.

#define IMG_H 128
#define IMG_W 128

__global__ __launch_bounds__(256) void st_warp_kernel(
    const float* __restrict__ img,   // B*128*128*3
    const float* __restrict__ Hm,    // B*9
    float* __restrict__ out)         // B*128*128
{
    // 64 blocks of 256 threads per batch image (16384 pixels)
    const int b     = blockIdx.x >> 6;
    const int chunk = blockIdx.x & 63;
    const int n     = (chunk << 8) + threadIdx.x;   // pixel index in [0,16384)
    const int i     = n >> 7;    // output row
    const int j     = n & 127;   // output col

    // H for this batch (uniform across block -> scalar loads)
    const float* Hb = Hm + b * 9;
    const float h00 = Hb[0], h01 = Hb[1], h02 = Hb[2];
    const float h10 = Hb[3], h11 = Hb[4], h12 = Hb[5];
    const float h20 = Hb[6], h21 = Hb[7], h22 = Hb[8];

    // meshgrid: linspace(-1,1,128) -> -1 + idx * (2/127)
    const float step = 2.0f / 127.0f;
    const float xt = -1.0f + step * (float)j;
    const float yt = -1.0f + step * (float)i;

    const float Tx = h00 * xt + h01 * yt + h02;
    const float Ty = h10 * xt + h11 * yt + h12;
    const float Tz = h20 * xt + h21 * yt + h22;

    const float xs = Tx / Tz;
    const float ys = Ty / Tz;

    // to pixel coords
    const float x = (xs + 1.0f) * 64.0f;   // * (W/2)
    const float y = (ys + 1.0f) * 64.0f;   // * (H/2)

    const float fx0 = floorf(x);
    const float fy0 = floorf(y);
    // clamp to int-safe range before conversion (benign H keeps these small,
    // but avoid UB on pathological values)
    int x0 = (int)fmaxf(fminf(fx0, 2.0e9f), -2.0e9f);
    int y0 = (int)fmaxf(fminf(fy0, 2.0e9f), -2.0e9f);
    int x1 = x0 + 1;
    int y1 = y0 + 1;
    x0 = min(max(x0, 0), IMG_W - 1);
    x1 = min(max(x1, 0), IMG_W - 1);
    y0 = min(max(y0, 0), IMG_H - 1);
    y1 = min(max(y1, 0), IMG_H - 1);

    // gather 4 taps of channel 0 (stride 3 floats)
    const float* imb = img + (size_t)b * (IMG_H * IMG_W * 3);
    const float Ia = imb[(y0 * IMG_W + x0) * 3];
    const float Ib = imb[(y1 * IMG_W + x0) * 3];
    const float Ic = imb[(y0 * IMG_W + x1) * 3];
    const float Id = imb[(y1 * IMG_W + x1) * 3];

    // weights from CLIPPED index floats (matches reference semantics)
    const float x0f = (float)x0, x1f = (float)x1;
    const float y0f = (float)y0, y1f = (float)y1;
    const float wa = (x1f - x) * (y1f - y);
    const float wb = (x1f - x) * (y - y0f);
    const float wc = (x - x0f) * (y1f - y);
    const float wd = (x - x0f) * (y - y0f);

    out[(size_t)b * (IMG_H * IMG_W) + n] = wa * Ia + wb * Ib + wc * Ic + wd * Id;
}

extern "C" void kernel_launch(void* const* d_in, const int* in_sizes, int n_in,
                              void* d_out, int out_size, void* d_ws, size_t ws_size,
                              hipStream_t stream) {
    const float* img = (const float*)d_in[0];   // (2048,128,128,3) f32
    const float* Hm  = (const float*)d_in[1];   // (2048,3,3) f32
    float* out = (float*)d_out;                 // (2048,128,128,1) f32

    const int B = in_sizes[1] / 9;              // 2048
    const int blocks = B * 64;                  // 64 blocks/batch, 256 thr/block
    st_warp_kernel<<<blocks, 256, 0, stream>>>(img, Hm, out);
}